// Round 4
// baseline (776.456 us; speedup 1.0000x reference)
//
#include <hip/hip_runtime.h>
#include <cstdint>

// DimeNet interaction block, MI355X/gfx950.  Round 4: software-pipelined
// staging (register prefetch of weight tiles across barriers/MFMA) + 128-row
// post tiles.  Round-3 baseline 616 us: all kernels latency-bound
// (MfmaUtil 11%, VALUBusy 9%, HBM 9%) on serial stage->barrier->MFMA loops.
//
// Dtypes: float tensors are f32; indices int32; out f32.
// Internals: f32 -> f16 MFMA operands, fp32 accumulate (absmax 0.031 @ thr 0.165).
// Memory: agg f32[E][H] aliased onto d_out; x_kj f16[E][H] in d_ws (sole use).

#define H 128
#define NB 8
#define NR 6
#define SBC 42
#define LDA 136   // f16 lane pad: 128 + 8
#define LDF 132   // f32 lane pad: 128 + 4

using f16x8 = __attribute__((ext_vector_type(8))) _Float16;
using f32x4 = __attribute__((ext_vector_type(4))) float;

__device__ __forceinline__ float silu_f(float v){
  return v / (1.f + __expf(-v));
}
__device__ __forceinline__ f16x8 pack8(float4 a, float4 b){
  f16x8 h;
  h[0]=(_Float16)a.x; h[1]=(_Float16)a.y; h[2]=(_Float16)a.z; h[3]=(_Float16)a.w;
  h[4]=(_Float16)b.x; h[5]=(_Float16)b.y; h[6]=(_Float16)b.z; h[7]=(_Float16)b.w;
  return h;
}

// Weight-tile register prefetch helpers: thread covers rows k0,k0+1 (k0=2*(tid&63)),
// cols c0..c0+31 (c0=(tid>>6)*32) of a 128x128 f32 matrix -> 16 float4.
__device__ __forceinline__ void wload(const float* __restrict__ w, int tid,
                                      float4* __restrict__ r){
  int k0 = (tid & 63) * 2;
  int c0 = (tid >> 6) * 32;
  const float4* p0 = reinterpret_cast<const float4*>(w + (size_t)k0*H + c0);
  const float4* p1 = reinterpret_cast<const float4*>(w + (size_t)(k0+1)*H + c0);
  #pragma unroll
  for (int i=0;i<8;i++){ r[i] = p0[i]; r[8+i] = p1[i]; }
}
// Write prefetched regs as transposed f16 [n][k] into LDS (paired-k u32 writes).
__device__ __forceinline__ void wstore(const float4* __restrict__ r,
                                       _Float16* __restrict__ sB, int tid){
  int k0 = (tid & 63) * 2;
  int c0 = (tid >> 6) * 32;
  #pragma unroll
  for (int i=0;i<8;i++){
    float a0[4] = {r[i].x,  r[i].y,  r[i].z,  r[i].w};
    float a1[4] = {r[8+i].x,r[8+i].y,r[8+i].z,r[8+i].w};
    #pragma unroll
    for (int j=0;j<4;j++){
      unsigned int bits =
          (unsigned int)__builtin_bit_cast(unsigned short, (_Float16)a0[j])
        | ((unsigned int)__builtin_bit_cast(unsigned short, (_Float16)a1[j]) << 16);
      *reinterpret_cast<unsigned int*>(&sB[(c0+i*4+j)*LDA + k0]) = bits;
    }
  }
}

// ---------------- edge: x_kj -> ws (f16), agg(init)=x_ji -> d_out (f32) ----------------
__global__ __launch_bounds__(256,2) void edge_kernel(
    const float* __restrict__ x,
    const float* __restrict__ radial,
    const float* __restrict__ w_rbf,
    const float* __restrict__ w_from,
    const float* __restrict__ b_from,
    const float* __restrict__ w_to,
    const float* __restrict__ b_to,
    _Float16* __restrict__ x_kj, float* __restrict__ agg, int E)
{
  __shared__ alignas(16) _Float16 sA[64*LDA];
  __shared__ alignas(16) _Float16 sB[128*LDA];
  __shared__ alignas(16) _Float16 sO[64*LDA];
  __shared__ float sRad[64*8];
  __shared__ float sWr[128*8];
  __shared__ float sBf[128];
  __shared__ float sBt[128];
  int tid = threadIdx.x;
  int e0 = blockIdx.x*64;
  int wave = tid>>6, lane = tid&63, l15 = lane&15, q = lane>>4;

  float4 wreg[16];
  wload(w_from, tid, wreg);          // prefetch w_from (hidden behind x staging)

  { // stage x tile (f32 -> f16), zero OOB rows
    int row = tid>>2, cs = (tid&3)*32;
    bool ok = (e0+row) < E;
    const float4* src = reinterpret_cast<const float4*>(x + (size_t)(e0+row)*H + cs);
    #pragma unroll
    for (int i=0;i<4;i++){
      float4 u0{0,0,0,0}, u1{0,0,0,0};
      if (ok){ u0 = src[2*i]; u1 = src[2*i+1]; }
      *reinterpret_cast<f16x8*>(&sA[row*LDA + cs + i*8]) = pack8(u0,u1);
    }
  }
  for (int i=tid; i<64*NR; i+=256){
    int r=i/NR, c=i%NR;
    sRad[r*8+c] = (e0+r < E) ? radial[(size_t)(e0+r)*NR + c] : 0.f;
  }
  for (int i=tid; i<NR*H; i+=256){
    int c=i>>7, n=i&127;
    sWr[n*8+c] = w_rbf[i];
  }
  if (tid < H){ sBf[tid] = b_from[tid]; sBt[tid] = b_to[tid]; }
  wstore(wreg, sB, tid);             // w_from -> LDS
  wload(w_to, tid, wreg);            // prefetch w_to (hidden behind GEMM1)
  __syncthreads();                   // B1

  f32x4 acc[8];
  auto gemm = [&](){
    #pragma unroll
    for (int nt=0;nt<8;nt++) acc[nt] = f32x4{0.f,0.f,0.f,0.f};
    int ar = (wave*16 + l15)*LDA;
    #pragma unroll
    for (int kk=0;kk<4;kk++){
      f16x8 a = *reinterpret_cast<const f16x8*>(&sA[ar + kk*32 + q*8]);
      #pragma unroll
      for (int nt=0;nt<8;nt++){
        f16x8 b = *reinterpret_cast<const f16x8*>(&sB[(nt*16+l15)*LDA + kk*32 + q*8]);
        acc[nt] = __builtin_amdgcn_mfma_f32_16x16x32_f16(a, b, acc[nt], 0,0,0);
      }
    }
  };

  gemm();  // x @ w_from
  __syncthreads();                   // B2: sB reads done
  #pragma unroll
  for (int nt=0;nt<8;nt++)
    #pragma unroll
    for (int r=0;r<4;r++){
      int rl = wave*16 + q*4 + r, col = nt*16 + l15;
      float v = silu_f(acc[nt][r] + sBf[col]);
      float rb = 0.f;
      #pragma unroll
      for (int c=0;c<NR;c++) rb += sRad[rl*8+c]*sWr[col*8+c];
      sO[rl*LDA+col] = (_Float16)(v*rb);
    }
  wstore(wreg, sB, tid);             // w_to -> LDS (sB free since B2)
  __syncthreads();                   // B3: sO + sB ready
  { // coalesced f16 store x_kj -> ws
    int row=tid>>2, cs=(tid&3)*32;
    if (e0+row < E)
      #pragma unroll
      for (int i=0;i<4;i++)
        *reinterpret_cast<f16x8*>(x_kj + (size_t)(e0+row)*H + cs + i*8) =
          *reinterpret_cast<const f16x8*>(&sO[row*LDA + cs + i*8]);
  }
  gemm();  // x @ w_to
  __syncthreads();                   // B4: sO store-reads done
  #pragma unroll
  for (int nt=0;nt<8;nt++)
    #pragma unroll
    for (int r=0;r<4;r++){
      int rl = wave*16 + q*4 + r, col = nt*16 + l15;
      sO[rl*LDA+col] = (_Float16)silu_f(acc[nt][r] + sBt[col]);
    }
  __syncthreads();                   // B5
  { // agg init = x_ji, f32 store into d_out
    int row=tid>>2, cs=(tid&3)*32;
    if (e0+row < E)
      #pragma unroll
      for (int i=0;i<4;i++){
        f16x8 v = *reinterpret_cast<const f16x8*>(&sO[row*LDA + cs + i*8]);
        float4 lo{(float)v[0],(float)v[1],(float)v[2],(float)v[3]};
        float4 hi{(float)v[4],(float)v[5],(float)v[6],(float)v[7]};
        float4* dp = reinterpret_cast<float4*>(agg + (size_t)(e0+row)*H + cs + i*8);
        dp[0] = lo; dp[1] = hi;
      }
  }
}

// ---------------- bilinear + f32 atomic scatter (pipelined W staging) ----------------
__global__ __launch_bounds__(256,2) void bilinear_kernel(
    const _Float16* __restrict__ x_kj,
    const float* __restrict__ sph,
    const float* __restrict__ w_sbf,
    const float* __restrict__ Wb,
    const int* __restrict__ e_from, const int* __restrict__ e_to,
    float* __restrict__ agg)
{
  __shared__ alignas(16) _Float16 gth[128*LDA];
  __shared__ alignas(16) _Float16 wch[128*LDA];   // also f32 scratch for sph rows
  __shared__ float ssb[128*NB];
  __shared__ float sw[SBC*NB];
  __shared__ int sdst[128];
  int tid = threadIdx.x;
  long long t0 = (long long)blockIdx.x * 128;
  int row = tid>>1, half = tid&1;

  // Prefetch W[:,0,:]: thread covers W[i=row, 0, half*64 .. +63] (16 float4).
  float4 wreg[16];
  {
    const float4* wp = reinterpret_cast<const float4*>(Wb + (size_t)row*1024 + half*64);
    #pragma unroll
    for (int u=0;u<16;u++) wreg[u] = wp[u];
  }

  { // gather x_kj rows (f16, from ws)
    int src = e_from[t0 + row];
    const f16x8* sp = reinterpret_cast<const f16x8*>(x_kj + (size_t)src*H + half*64);
    f16x8* dp = reinterpret_cast<f16x8*>(&gth[row*LDA + half*64]);
    #pragma unroll
    for (int i=0;i<8;i++) dp[i] = sp[i];
  }
  { // stage 128 spherical rows (f32) into wch scratch, coalesced float4
    float4* scr = reinterpret_cast<float4*>(wch);
    const float4* g = reinterpret_cast<const float4*>(sph + t0*SBC);
    for (int i=tid; i<128*SBC/4; i+=256) scr[i] = g[i];
  }
  for (int i=tid; i<SBC*NB; i+=256) sw[i] = w_sbf[i];
  if (tid < 128) sdst[tid] = e_to[t0 + tid];
  __syncthreads();                   // gth / sph-scratch / sw ready
  { // inline sbf: row=tid>>1, cols half*4..half*4+3
    const float* srow = reinterpret_cast<const float*>(wch) + row*SBC;
    float a4[4] = {0.f,0.f,0.f,0.f};
    for (int c=0;c<SBC;c++){
      float v = srow[c];
      #pragma unroll
      for (int cc=0;cc<4;cc++) a4[cc] += v * sw[c*NB + half*4 + cc];
    }
    #pragma unroll
    for (int cc=0;cc<4;cc++) ssb[row*NB + half*4 + cc] = a4[cc];
  }

  int wave = tid>>6, lane = tid&63, l15 = lane&15, q = lane>>4;
  int m0 = wave*32;
  f32x4 acc[2][8];
  #pragma unroll
  for (int mt=0;mt<2;mt++)
    #pragma unroll
    for (int nt=0;nt<8;nt++) acc[mt][nt] = f32x4{0.f,0.f,0.f,0.f};

  for (int jj=0;jj<NB;jj++){
    __syncthreads();   // sbf-scratch reads / prev-jj wch MFMA reads complete
    { // write prefetched W chunk (f32 regs -> f16 LDS, b128 writes)
      f16x8* dp = reinterpret_cast<f16x8*>(&wch[row*LDA + half*64]);
      #pragma unroll
      for (int u=0;u<8;u++) dp[u] = pack8(wreg[2*u], wreg[2*u+1]);
    }
    if (jj < NB-1){ // prefetch next chunk; overlaps MFMA below + both barriers
      const float4* wp = reinterpret_cast<const float4*>(Wb + (size_t)row*1024 + (jj+1)*128 + half*64);
      #pragma unroll
      for (int u=0;u<16;u++) wreg[u] = wp[u];
    }
    __syncthreads();
    _Float16 s0 = (_Float16)ssb[(m0+l15)*NB + jj];
    _Float16 s1 = (_Float16)ssb[(m0+16+l15)*NB + jj];
    #pragma unroll
    for (int kk=0;kk<4;kk++){
      f16x8 a0 = *reinterpret_cast<const f16x8*>(&gth[(m0+l15)*LDA + kk*32 + q*8]);
      f16x8 a1 = *reinterpret_cast<const f16x8*>(&gth[(m0+16+l15)*LDA + kk*32 + q*8]);
      a0 *= s0; a1 *= s1;    // A-fragment = sbf[w][jj] * gathered[w][l]
      #pragma unroll
      for (int nt=0;nt<8;nt++){
        f16x8 b = *reinterpret_cast<const f16x8*>(&wch[(nt*16+l15)*LDA + kk*32 + q*8]);
        acc[0][nt] = __builtin_amdgcn_mfma_f32_16x16x32_f16(a0, b, acc[0][nt], 0,0,0);
        acc[1][nt] = __builtin_amdgcn_mfma_f32_16x16x32_f16(a1, b, acc[1][nt], 0,0,0);
      }
    }
  }
  // f32 atomic scatter (native global_atomic_add_f32; avg 2.6 writers/row)
  #pragma unroll
  for (int mt=0;mt<2;mt++)
    #pragma unroll
    for (int nt=0;nt<8;nt++)
      #pragma unroll
      for (int r=0;r<4;r++){
        int rl = m0 + mt*16 + q*4 + r;
        int col = nt*16 + l15;
        unsafeAtomicAdd(&agg[(size_t)sdst[rl]*H + col], acc[mt][nt][r]);
      }
}

// ---------------- post: 128-row tiles, 7 pipelined GEMM stages -> f32 out ----------------
__global__ __launch_bounds__(256,2) void post_kernel(
    const float* __restrict__ x, const float* __restrict__ agg,
    const float* __restrict__ rb_w, const float* __restrict__ rb_b,
    const float* __restrict__ lin_w, const float* __restrict__ lin_b,
    const float* __restrict__ ra_w, const float* __restrict__ ra_b,
    float* __restrict__ out, int E)
{
  // unified smem: sIn (34816 B) | sW (34816 B); final f32 scratch reuses both
  __shared__ alignas(16) _Float16 smem[2*128*LDA];
  __shared__ float sBias[128];
  _Float16* sIn = smem;
  _Float16* sW  = smem + 128*LDA;
  int tid = threadIdx.x, e0 = blockIdx.x*128;
  int wave = tid>>6, lane = tid&63, l15 = lane&15, q = lane>>4;
  int m0 = wave*32;

  const float* wptr[7] = {rb_w, rb_w+16384, lin_w, ra_w, ra_w+16384, ra_w+32768, ra_w+49152};
  const float* bptr[7] = {rb_b, rb_b+128, lin_b, ra_b, ra_b+128, ra_b+256, ra_b+384};

  float4 wreg[16];
  wload(wptr[0], tid, wreg);         // stage-0 weights, hidden behind h0 staging

  { // h0 = agg (= x_ji + scattered msg), f32 -> f16; 128 rows
    int row = tid>>1, half = tid&1;  // 512 B per row, thread-pair per row
    bool ok = (e0+row) < E;
    const float4* ap = reinterpret_cast<const float4*>(agg + (size_t)(e0+row)*H + half*64);
    #pragma unroll
    for (int i=0;i<8;i++){
      float4 u0{0,0,0,0}, u1{0,0,0,0};
      if (ok){ u0 = ap[2*i]; u1 = ap[2*i+1]; }
      *reinterpret_cast<f16x8*>(&sIn[row*LDA + half*64 + i*8]) = pack8(u0,u1);
    }
  }
  __syncthreads();
  float h[2][8][4];   // C-layout: row = m0+mt*16+q*4+r, col = nt*16+l15
  #pragma unroll
  for (int mt=0;mt<2;mt++)
    #pragma unroll
    for (int nt=0;nt<8;nt++)
      #pragma unroll
      for (int r=0;r<4;r++)
        h[mt][nt][r] = (float)sIn[(m0+mt*16+q*4+r)*LDA + nt*16 + l15];

  f32x4 acc[2][8];
  #pragma unroll
  for (int s=0;s<7;s++){
    __syncthreads();                 // A: prev MFMA sW reads + epilogue sIn writes settled
    wstore(wreg, sW, tid);
    if (tid < H) sBias[tid] = bptr[s][tid];
    if (s < 6) wload(wptr[s+1], tid, wreg);  // overlaps MFMA below
    __syncthreads();                 // B: sW/sBias ready
    #pragma unroll
    for (int mt=0;mt<2;mt++)
      #pragma unroll
      for (int nt=0;nt<8;nt++) acc[mt][nt] = f32x4{0.f,0.f,0.f,0.f};
    #pragma unroll
    for (int kk=0;kk<4;kk++){
      f16x8 a0 = *reinterpret_cast<const f16x8*>(&sIn[(m0+l15)*LDA + kk*32 + q*8]);
      f16x8 a1 = *reinterpret_cast<const f16x8*>(&sIn[(m0+16+l15)*LDA + kk*32 + q*8]);
      #pragma unroll
      for (int nt=0;nt<8;nt++){
        f16x8 b = *reinterpret_cast<const f16x8*>(&sW[(nt*16+l15)*LDA + kk*32 + q*8]);
        acc[0][nt] = __builtin_amdgcn_mfma_f32_16x16x32_f16(a0, b, acc[0][nt], 0,0,0);
        acc[1][nt] = __builtin_amdgcn_mfma_f32_16x16x32_f16(a1, b, acc[1][nt], 0,0,0);
      }
    }
    __syncthreads();                 // C: MFMA reads done -> epilogue may write sIn
    #pragma unroll
    for (int mt=0;mt<2;mt++)
      #pragma unroll
      for (int nt=0;nt<8;nt++)
        #pragma unroll
        for (int r=0;r<4;r++){
          int rl = m0 + mt*16 + q*4 + r, col = nt*16 + l15;
          float v = silu_f(acc[mt][nt][r] + sBias[col]);
          if (s==0 || s==3 || s==5){            // first half of residual MLP
            sIn[rl*LDA+col] = (_Float16)v;
          } else if (s==1 || s==4){             // close residual: h += v
            h[mt][nt][r] += v;
            sIn[rl*LDA+col] = (_Float16)h[mt][nt][r];
          } else if (s==2){                     // h = silu(..) + x
            bool ok = (e0+rl) < E;
            float xv = ok ? x[(size_t)(e0+rl)*H + col] : 0.f;
            h[mt][nt][r] = v + xv;
            sIn[rl*LDA+col] = (_Float16)h[mt][nt][r];
          } else {                              // s==6: final h += v -> f32 scratch
            h[mt][nt][r] += v;
            float* scr = reinterpret_cast<float*>(smem);
            scr[rl*LDF+col] = h[mt][nt][r];
          }
        }
  }
  __syncthreads();
  { // coalesced f32 output store
    const float* scr = reinterpret_cast<const float*>(smem);
    int row = tid>>1, half = tid&1;
    if (e0+row < E){
      float4* dp = reinterpret_cast<float4*>(out + (size_t)(e0+row)*H + half*64);
      #pragma unroll
      for (int i=0;i<16;i++)
        dp[i] = *reinterpret_cast<const float4*>(&scr[row*LDF + half*64 + i*4]);
    }
  }
}

extern "C" void kernel_launch(void* const* d_in, const int* in_sizes, int n_in,
                              void* d_out, int out_size, void* d_ws, size_t ws_size,
                              hipStream_t stream)
{
  const float* x      = (const float*)d_in[0];
  const float* radial = (const float*)d_in[1];
  const float* sph    = (const float*)d_in[2];
  const int* e_from   = (const int*)d_in[3];
  const int* e_to     = (const int*)d_in[4];
  const float* w_rbf  = (const float*)d_in[5];
  const float* w_sbf  = (const float*)d_in[6];
  const float* w_from = (const float*)d_in[7];
  const float* b_from = (const float*)d_in[8];
  const float* w_to   = (const float*)d_in[9];
  const float* b_to   = (const float*)d_in[10];
  const float* Wb     = (const float*)d_in[11];
  const float* rb_w   = (const float*)d_in[12];
  const float* rb_b   = (const float*)d_in[13];
  const float* lin_w  = (const float*)d_in[14];
  const float* lin_b  = (const float*)d_in[15];
  const float* ra_w   = (const float*)d_in[16];
  const float* ra_b   = (const float*)d_in[17];

  int E = in_sizes[0] / H;      // 100000
  int T = in_sizes[3];          // 262144

  float*    agg  = (float*)d_out;      // f32 [E][H], 1:1 with output rows
  _Float16* x_kj = (_Float16*)d_ws;    // f16 [E][H], 25.6 MB, sole ws use

  edge_kernel<<<(E+63)/64, 256, 0, stream>>>(x, radial, w_rbf, w_from, b_from,
                                             w_to, b_to, x_kj, agg, E);
  bilinear_kernel<<<T/128, 256, 0, stream>>>(x_kj, sph, w_sbf, Wb, e_from, e_to, agg);
  post_kernel<<<(E+127)/128, 256, 0, stream>>>(x, agg, rb_w, rb_b, lin_w, lin_b,
                                               ra_w, ra_b, (float*)d_out, E);
}

// Round 5
// 610.577 us; speedup vs baseline: 1.2717x; 1.2717x over previous
//
#include <hip/hip_runtime.h>
#include <cstdint>

// DimeNet interaction block, MI355X/gfx950.  Round 5.
// Round-4 regression root cause (counters): post WRITE_SIZE 213 MB vs 51 MB
// output -> register spills from 128-row tiles + 64-VGPR f32 weight prefetch.
// Fix: one-shot prep kernel rewrites all weights into MFMA-B-fragment-linear
// f16 (element order ((nt*4+kk)*64+lane)*8+j), so hot kernels stage weights
// with a 32 KB coalesced copy (8 uint4/thread prefetch = 32 VGPRs, no
// transpose, no convert, conflict-free unpadded LDS reads).  post back to
// 64-row tiles, 2 barriers/stage, LDS 50.7 KB -> 3 blocks/CU.
//
// Dtypes: float tensors f32; indices int32; out f32.
// Internals: f16 MFMA operands, fp32 accumulate (absmax 0.031 @ thr 0.165).
// Memory: agg f32[E][H] aliased onto d_out; d_ws = x_kj f16[E][H] (25.6 MB)
//         + 9 frag weights (288 KB) + 8 frag W chunks (256 KB).

#define H 128
#define NB 8
#define NR 6
#define SBC 42
#define LDA 136    // f16 lane pad for row-major tiles (16B-aligned rows)
#define LDF 132    // f32 lane pad
#define WFRAG 16384  // f16 elems per fragment-linear 128x128 weight

using f16x8 = __attribute__((ext_vector_type(8))) _Float16;
using f32x4 = __attribute__((ext_vector_type(4))) float;

__device__ __forceinline__ float silu_f(float v){
  return v / (1.f + __expf(-v));
}
__device__ __forceinline__ f16x8 pack8(float4 a, float4 b){
  f16x8 h;
  h[0]=(_Float16)a.x; h[1]=(_Float16)a.y; h[2]=(_Float16)a.z; h[3]=(_Float16)a.w;
  h[4]=(_Float16)b.x; h[5]=(_Float16)b.y; h[6]=(_Float16)b.z; h[7]=(_Float16)b.w;
  return h;
}

// ---------------- prep: weights -> MFMA-B-fragment-linear f16 ----------------
// wf slots: 0=w_from 1=w_to 2=rb0 3=rb1 4=lin 5=ra00 6=ra01 7=ra10 8=ra11
// Mapping: wf[m][c*8+j] = (f16) w_m[(kk*32+q*8+j)*128 + nt*16+l15]
//   where c=(nt*4+kk)*64+l, q=l>>4, l15=l&15  (= lane l's B-fragment for
//   tile (nt,kk) of GEMM h@w).
// Wf slots per j: Wf[j][c*8+jj2] = W[i=nt*16+l15][j][l=kk*32+q*8+jj2].
__global__ void prep_kernel(const float* __restrict__ w_from,
                            const float* __restrict__ w_to,
                            const float* __restrict__ rb_w,
                            const float* __restrict__ lin_w,
                            const float* __restrict__ ra_w,
                            const float* __restrict__ Wb,
                            _Float16* __restrict__ wf,
                            _Float16* __restrict__ Wf)
{
  int idx = blockIdx.x*256 + threadIdx.x;
  if (blockIdx.x < 72){                 // 72*256 == 9*2048 exactly
    int m = idx >> 11, c = idx & 2047;
    int nt = c >> 8, kk = (c>>6)&3, l = c&63, q = l>>4, l15 = l&15;
    const float* src;
    switch(m){
      case 0: src = w_from;       break;
      case 1: src = w_to;         break;
      case 2: src = rb_w;         break;
      case 3: src = rb_w + 16384; break;
      case 4: src = lin_w;        break;
      case 5: src = ra_w;         break;
      case 6: src = ra_w + 16384; break;
      case 7: src = ra_w + 32768; break;
      default: src = ra_w + 49152; break;
    }
    const float* p = src + (size_t)(kk*32 + q*8)*H + nt*16 + l15;
    f16x8 o;
    #pragma unroll
    for (int j=0;j<8;j++) o[j] = (_Float16)p[(size_t)j*H];
    *reinterpret_cast<f16x8*>(wf + (size_t)m*WFRAG + c*8) = o;
  } else {
    int t = idx - 72*256;               // < 16384 (64 blocks)
    int j = t >> 11, c = t & 2047;
    int nt = c >> 8, kk = (c>>6)&3, l = c&63, q = l>>4, l15 = l&15;
    const float4* p = reinterpret_cast<const float4*>(
        Wb + ((size_t)(nt*16+l15)*NB + j)*H + kk*32 + q*8);
    *reinterpret_cast<f16x8*>(Wf + (size_t)j*WFRAG + c*8) = pack8(p[0], p[1]);
  }
}

// ---------------- edge: x_kj -> ws (f16), agg(init)=x_ji -> d_out (f32) ----------------
__global__ __launch_bounds__(256,2) void edge_kernel(
    const float* __restrict__ x,
    const float* __restrict__ radial,
    const float* __restrict__ w_rbf,
    const _Float16* __restrict__ wf,
    const float* __restrict__ b_from,
    const float* __restrict__ b_to,
    _Float16* __restrict__ x_kj, float* __restrict__ agg, int E)
{
  __shared__ alignas(16) _Float16 sA[64*LDA];
  __shared__ alignas(16) _Float16 sB[WFRAG];
  __shared__ alignas(16) _Float16 sO[64*LDA];
  __shared__ float sRad[64*8];
  __shared__ float sWr[128*8];
  __shared__ float sBf[128];
  __shared__ float sBt[128];
  int tid = threadIdx.x;
  int e0 = blockIdx.x*64;
  int wave = tid>>6, lane = tid&63, l15 = lane&15, q = lane>>4;

  const uint4* wfu = reinterpret_cast<const uint4*>(wf);           // w_from
  const uint4* wtu = reinterpret_cast<const uint4*>(wf + WFRAG);   // w_to
  uint4* sBu = reinterpret_cast<uint4*>(sB);
  uint4 wr[8];
  #pragma unroll
  for (int i=0;i<8;i++) wr[i] = wfu[i*256 + tid];   // prefetch w_from

  { // stage x tile (f32 -> f16), zero OOB rows
    int row = tid>>2, cs = (tid&3)*32;
    bool ok = (e0+row) < E;
    const float4* src = reinterpret_cast<const float4*>(x + (size_t)(e0+row)*H + cs);
    #pragma unroll
    for (int i=0;i<4;i++){
      float4 u0{0,0,0,0}, u1{0,0,0,0};
      if (ok){ u0 = src[2*i]; u1 = src[2*i+1]; }
      *reinterpret_cast<f16x8*>(&sA[row*LDA + cs + i*8]) = pack8(u0,u1);
    }
  }
  for (int i=tid; i<64*NR; i+=256){
    int r=i/NR, c=i%NR;
    sRad[r*8+c] = (e0+r < E) ? radial[(size_t)(e0+r)*NR + c] : 0.f;
  }
  for (int i=tid; i<NR*H; i+=256){
    int c=i>>7, n=i&127;
    sWr[n*8+c] = w_rbf[i];
  }
  if (tid < H){ sBf[tid] = b_from[tid]; sBt[tid] = b_to[tid]; }
  #pragma unroll
  for (int i=0;i<8;i++) sBu[i*256 + tid] = wr[i];   // w_from -> LDS
  #pragma unroll
  for (int i=0;i<8;i++) wr[i] = wtu[i*256 + tid];   // prefetch w_to (in flight
                                                    // across B1 + GEMM1 + B2)
  __syncthreads();                   // B1

  f32x4 acc[8];
  auto gemm = [&](){
    #pragma unroll
    for (int nt=0;nt<8;nt++) acc[nt] = f32x4{0.f,0.f,0.f,0.f};
    int ar = (wave*16 + l15)*LDA;
    #pragma unroll
    for (int kk=0;kk<4;kk++){
      f16x8 a = *reinterpret_cast<const f16x8*>(&sA[ar + kk*32 + q*8]);
      #pragma unroll
      for (int nt=0;nt<8;nt++){
        f16x8 b = *reinterpret_cast<const f16x8*>(&sB[((nt*4+kk)*64 + lane)*8]);
        acc[nt] = __builtin_amdgcn_mfma_f32_16x16x32_f16(a, b, acc[nt], 0,0,0);
      }
    }
  };

  gemm();  // x @ w_from
  __syncthreads();                   // B2: sB reads done
  #pragma unroll
  for (int nt=0;nt<8;nt++)
    #pragma unroll
    for (int r=0;r<4;r++){
      int rl = wave*16 + q*4 + r, col = nt*16 + l15;
      float v = silu_f(acc[nt][r] + sBf[col]);
      float rb = 0.f;
      #pragma unroll
      for (int c=0;c<NR;c++) rb += sRad[rl*8+c]*sWr[col*8+c];
      sO[rl*LDA+col] = (_Float16)(v*rb);
    }
  #pragma unroll
  for (int i=0;i<8;i++) sBu[i*256 + tid] = wr[i];   // w_to -> LDS
  __syncthreads();                   // B3: sO + sB ready
  { // coalesced f16 store x_kj -> ws
    int row=tid>>2, cs=(tid&3)*32;
    if (e0+row < E)
      #pragma unroll
      for (int i=0;i<4;i++)
        *reinterpret_cast<f16x8*>(x_kj + (size_t)(e0+row)*H + cs + i*8) =
          *reinterpret_cast<const f16x8*>(&sO[row*LDA + cs + i*8]);
  }
  gemm();  // x @ w_to
  __syncthreads();                   // B4: sO store-reads done
  #pragma unroll
  for (int nt=0;nt<8;nt++)
    #pragma unroll
    for (int r=0;r<4;r++){
      int rl = wave*16 + q*4 + r, col = nt*16 + l15;
      sO[rl*LDA+col] = (_Float16)silu_f(acc[nt][r] + sBt[col]);
    }
  __syncthreads();                   // B5
  { // agg init = x_ji, f32 store into d_out
    int row=tid>>2, cs=(tid&3)*32;
    if (e0+row < E)
      #pragma unroll
      for (int i=0;i<4;i++){
        f16x8 v = *reinterpret_cast<const f16x8*>(&sO[row*LDA + cs + i*8]);
        float4 lo{(float)v[0],(float)v[1],(float)v[2],(float)v[3]};
        float4 hi{(float)v[4],(float)v[5],(float)v[6],(float)v[7]};
        float4* dp = reinterpret_cast<float4*>(agg + (size_t)(e0+row)*H + cs + i*8);
        dp[0] = lo; dp[1] = hi;
      }
  }
}

// ---------------- bilinear + f32 atomic scatter ----------------
__global__ __launch_bounds__(256,2) void bilinear_kernel(
    const _Float16* __restrict__ x_kj,
    const float* __restrict__ sph,
    const float* __restrict__ w_sbf,
    const _Float16* __restrict__ Wf,
    const int* __restrict__ e_from, const int* __restrict__ e_to,
    float* __restrict__ agg)
{
  __shared__ alignas(16) _Float16 gth[128*LDA];
  __shared__ alignas(16) _Float16 wch[WFRAG];   // frag W chunk; f32 sph scratch pre-loop
  __shared__ float ssb[128*NB];
  __shared__ float sw[SBC*NB];
  __shared__ int sdst[128];
  int tid = threadIdx.x;
  long long t0 = (long long)blockIdx.x * 128;
  int row = tid>>1, half = tid&1;

  uint4 wr[8];
  {
    const uint4* wp = reinterpret_cast<const uint4*>(Wf);   // Wf[0]
    #pragma unroll
    for (int u=0;u<8;u++) wr[u] = wp[u*256 + tid];
  }

  { // gather x_kj rows (f16, from ws)
    int src = e_from[t0 + row];
    const f16x8* sp = reinterpret_cast<const f16x8*>(x_kj + (size_t)src*H + half*64);
    f16x8* dp = reinterpret_cast<f16x8*>(&gth[row*LDA + half*64]);
    #pragma unroll
    for (int i=0;i<8;i++) dp[i] = sp[i];
  }
  { // stage 128 spherical rows (f32) into wch scratch (21.5 KB <= 32 KB)
    float4* scr = reinterpret_cast<float4*>(wch);
    const float4* g = reinterpret_cast<const float4*>(sph + t0*SBC);
    for (int i=tid; i<128*SBC/4; i+=256) scr[i] = g[i];
  }
  for (int i=tid; i<SBC*NB; i+=256) sw[i] = w_sbf[i];
  if (tid < 128) sdst[tid] = e_to[t0 + tid];
  __syncthreads();
  { // inline sbf: row=tid>>1, cols half*4..half*4+3
    const float* srow = reinterpret_cast<const float*>(wch) + row*SBC;
    float a4[4] = {0.f,0.f,0.f,0.f};
    for (int c=0;c<SBC;c++){
      float v = srow[c];
      #pragma unroll
      for (int cc=0;cc<4;cc++) a4[cc] += v * sw[c*NB + half*4 + cc];
    }
    #pragma unroll
    for (int cc=0;cc<4;cc++) ssb[row*NB + half*4 + cc] = a4[cc];
  }

  int wave = tid>>6, lane = tid&63, l15 = lane&15, q = lane>>4;
  int m0 = wave*32;
  f32x4 acc[2][8];
  #pragma unroll
  for (int mt=0;mt<2;mt++)
    #pragma unroll
    for (int nt=0;nt<8;nt++) acc[mt][nt] = f32x4{0.f,0.f,0.f,0.f};

  uint4* wchu = reinterpret_cast<uint4*>(wch);
  for (int jj=0;jj<NB;jj++){
    __syncthreads();   // iter0: sbf-scratch reads done; else prev MFMA wch reads
    #pragma unroll
    for (int u=0;u<8;u++) wchu[u*256 + tid] = wr[u];
    if (jj < NB-1){    // prefetch next chunk; in flight across barrier + MFMA
      const uint4* wp = reinterpret_cast<const uint4*>(Wf + (size_t)(jj+1)*WFRAG);
      #pragma unroll
      for (int u=0;u<8;u++) wr[u] = wp[u*256 + tid];
    }
    __syncthreads();
    _Float16 s0 = (_Float16)ssb[(m0+l15)*NB + jj];
    _Float16 s1 = (_Float16)ssb[(m0+16+l15)*NB + jj];
    #pragma unroll
    for (int kk=0;kk<4;kk++){
      f16x8 a0 = *reinterpret_cast<const f16x8*>(&gth[(m0+l15)*LDA + kk*32 + q*8]);
      f16x8 a1 = *reinterpret_cast<const f16x8*>(&gth[(m0+16+l15)*LDA + kk*32 + q*8]);
      a0 *= s0; a1 *= s1;    // A-fragment = sbf[w][jj] * gathered[w][l]
      #pragma unroll
      for (int nt=0;nt<8;nt++){
        f16x8 b = *reinterpret_cast<const f16x8*>(&wch[((nt*4+kk)*64 + lane)*8]);
        acc[0][nt] = __builtin_amdgcn_mfma_f32_16x16x32_f16(a0, b, acc[0][nt], 0,0,0);
        acc[1][nt] = __builtin_amdgcn_mfma_f32_16x16x32_f16(a1, b, acc[1][nt], 0,0,0);
      }
    }
  }
  // f32 atomic scatter (native global_atomic_add_f32; avg 2.6 writers/row)
  #pragma unroll
  for (int mt=0;mt<2;mt++)
    #pragma unroll
    for (int nt=0;nt<8;nt++)
      #pragma unroll
      for (int r=0;r<4;r++){
        int rl = m0 + mt*16 + q*4 + r;
        int col = nt*16 + l15;
        unsafeAtomicAdd(&agg[(size_t)sdst[rl]*H + col], acc[mt][nt][r]);
      }
}

// ---------------- post: 64-row tiles, 7 GEMM stages, 2 barriers/stage ----------------
__global__ __launch_bounds__(256,3) void post_kernel(
    const float* __restrict__ x, const float* __restrict__ agg,
    const _Float16* __restrict__ wf,
    const float* __restrict__ rb_b, const float* __restrict__ lin_b,
    const float* __restrict__ ra_b,
    float* __restrict__ out, int E)
{
  // unified: sIn (17408 B) | sW (32768 B); f32 out scratch (33792 B) reuses both
  __shared__ alignas(16) _Float16 smem[64*LDA + WFRAG];
  __shared__ float sBias[128];
  _Float16* sIn = smem;
  _Float16* sW  = smem + 64*LDA;
  uint4* sWu = reinterpret_cast<uint4*>(sW);
  int tid = threadIdx.x, e0 = blockIdx.x*64;
  int wave = tid>>6, lane = tid&63, l15 = lane&15, q = lane>>4;

  const float* bptr[7] = {rb_b, rb_b+128, lin_b, ra_b, ra_b+128, ra_b+256, ra_b+384};

  uint4 wr[8];
  {
    const uint4* wp = reinterpret_cast<const uint4*>(wf + 2*WFRAG);  // stage 0 = rb0
    #pragma unroll
    for (int u=0;u<8;u++) wr[u] = wp[u*256 + tid];
  }

  { // h0 = agg (= x_ji + scattered msg), f32 -> f16
    int row=tid>>2, cs=(tid&3)*32;
    bool ok = (e0+row) < E;
    const float4* ap = reinterpret_cast<const float4*>(agg + (size_t)(e0+row)*H + cs);
    #pragma unroll
    for (int i=0;i<4;i++){
      float4 u0{0,0,0,0}, u1{0,0,0,0};
      if (ok){ u0 = ap[2*i]; u1 = ap[2*i+1]; }
      *reinterpret_cast<f16x8*>(&sIn[row*LDA + cs + i*8]) = pack8(u0,u1);
    }
  }
  __syncthreads();
  float h[8][4];   // C-layout: row=wave*16+q*4+r, col=nt*16+l15
  #pragma unroll
  for (int nt=0;nt<8;nt++)
    #pragma unroll
    for (int r=0;r<4;r++)
      h[nt][r] = (float)sIn[(wave*16+q*4+r)*LDA + nt*16 + l15];

  f32x4 acc[8];
  #pragma unroll
  for (int s=0;s<7;s++){
    // entering: sW free (prev MFMA behind barrier C), sIn holds stage input
    #pragma unroll
    for (int u=0;u<8;u++) sWu[u*256 + tid] = wr[u];
    if (tid < H) sBias[tid] = bptr[s][tid];
    if (s < 6){   // prefetch next stage's weights; overlaps MFMA below
      const uint4* wp = reinterpret_cast<const uint4*>(wf + (size_t)(3+s)*WFRAG);
      #pragma unroll
      for (int u=0;u<8;u++) wr[u] = wp[u*256 + tid];
    }
    __syncthreads();                 // B: sW/sBias ready, sIn epilogue writes visible
    #pragma unroll
    for (int nt=0;nt<8;nt++) acc[nt] = f32x4{0.f,0.f,0.f,0.f};
    int ar = (wave*16 + l15)*LDA;
    #pragma unroll
    for (int kk=0;kk<4;kk++){
      f16x8 a = *reinterpret_cast<const f16x8*>(&sIn[ar + kk*32 + q*8]);
      #pragma unroll
      for (int nt=0;nt<8;nt++){
        f16x8 b = *reinterpret_cast<const f16x8*>(&sW[((nt*4+kk)*64 + lane)*8]);
        acc[nt] = __builtin_amdgcn_mfma_f32_16x16x32_f16(a, b, acc[nt], 0,0,0);
      }
    }
    __syncthreads();                 // C: MFMA reads done -> epilogue may write sIn
    #pragma unroll
    for (int nt=0;nt<8;nt++)
      #pragma unroll
      for (int r=0;r<4;r++){
        int rl = wave*16 + q*4 + r, col = nt*16 + l15;
        float v = silu_f(acc[nt][r] + sBias[col]);
        if (s==0 || s==3 || s==5){            // first half of residual MLP
          sIn[rl*LDA+col] = (_Float16)v;
        } else if (s==1 || s==4){             // close residual: h += v
          h[nt][r] += v;
          sIn[rl*LDA+col] = (_Float16)h[nt][r];
        } else if (s==2){                     // h = silu(..) + x
          bool ok = (e0+rl) < E;
          float xv = ok ? x[(size_t)(e0+rl)*H + col] : 0.f;
          h[nt][r] = v + xv;
          sIn[rl*LDA+col] = (_Float16)h[nt][r];
        } else {                              // s==6: final h += v -> f32 scratch
          h[nt][r] += v;
          reinterpret_cast<float*>(smem)[rl*LDF+col] = h[nt][r];
        }
      }
  }
  __syncthreads();
  { // coalesced f32 output store
    const float* scr = reinterpret_cast<const float*>(smem);
    int row=tid>>2, cs=(tid&3)*32;
    if (e0+row < E)
      #pragma unroll
      for (int i=0;i<8;i++)
        *reinterpret_cast<float4*>(out + (size_t)(e0+row)*H + cs + i*4) =
          *reinterpret_cast<const float4*>(&scr[row*LDF + cs + i*4]);
  }
}

extern "C" void kernel_launch(void* const* d_in, const int* in_sizes, int n_in,
                              void* d_out, int out_size, void* d_ws, size_t ws_size,
                              hipStream_t stream)
{
  const float* x      = (const float*)d_in[0];
  const float* radial = (const float*)d_in[1];
  const float* sph    = (const float*)d_in[2];
  const int* e_from   = (const int*)d_in[3];
  const int* e_to     = (const int*)d_in[4];
  const float* w_rbf  = (const float*)d_in[5];
  const float* w_sbf  = (const float*)d_in[6];
  const float* w_from = (const float*)d_in[7];
  const float* b_from = (const float*)d_in[8];
  const float* w_to   = (const float*)d_in[9];
  const float* b_to   = (const float*)d_in[10];
  const float* Wb     = (const float*)d_in[11];
  const float* rb_w   = (const float*)d_in[12];
  const float* rb_b   = (const float*)d_in[13];
  const float* lin_w  = (const float*)d_in[14];
  const float* lin_b  = (const float*)d_in[15];
  const float* ra_w   = (const float*)d_in[16];
  const float* ra_b   = (const float*)d_in[17];

  int E = in_sizes[0] / H;      // 100000
  int T = in_sizes[3];          // 262144

  float*    agg  = (float*)d_out;        // f32 [E][H], 1:1 with output rows
  char* ws = (char*)d_ws;
  _Float16* x_kj = (_Float16*)ws;                           // 25.6 MB
  _Float16* wf   = (_Float16*)(ws + (size_t)E*H*2);         // 9*32 KB frag weights
  _Float16* Wf   = wf + 9*WFRAG;                            // 8*32 KB frag W

  prep_kernel<<<136, 256, 0, stream>>>(w_from, w_to, rb_w, lin_w, ra_w, Wb, wf, Wf);
  edge_kernel<<<(E+63)/64, 256, 0, stream>>>(x, radial, w_rbf, wf, b_from, b_to,
                                             x_kj, agg, E);
  bilinear_kernel<<<T/128, 256, 0, stream>>>(x_kj, sph, w_sbf, Wf, e_from, e_to, agg);
  post_kernel<<<(E+63)/64, 256, 0, stream>>>(x, agg, wf, rb_b, lin_b, ra_b,
                                             (float*)d_out, E);
}